// Round 19
// baseline (200.809 us; speedup 1.0000x reference)
//
#include <hip/hip_runtime.h>

#define HID    128
#define SEQ    512
#define BATCH  256
#define DIM    300
#define VOCAB  50000

typedef short bf16x8 __attribute__((ext_vector_type(8)));   // 8 bf16 = 4 VGPR
typedef float f32x4  __attribute__((ext_vector_type(4)));
typedef __fp16 half2_t __attribute__((ext_vector_type(2))); // matches cvt_pkrtz

#define KP     320      // padded K (10 x 32)
#define LST    328      // LDS row stride in bf16 (656 B, 16B-aligned)
#define TROWS  32       // vocab rows per tile
#define NTILES ((VOCAB + TROWS - 1) / TROWS)   // 1563

__device__ __forceinline__ unsigned bf16_rtne(float v)
{
    unsigned u = __float_as_uint(v);
    return (u + 0x7FFFu + ((u >> 16) & 1u)) >> 16;
}

// ---------------------------------------------------------------------------
// Kernel A (R15-proven, ~33 µs): persistent MFMA proj — byte-identical.
// ---------------------------------------------------------------------------
__global__ __launch_bounds__(512)
void proj_persist(const float* __restrict__ emb,
                  const float* __restrict__ Wih,
                  const float* __restrict__ bih,
                  const float* __restrict__ bhh,
                  float* __restrict__ P)
{
    __shared__ unsigned short Bt[128 * LST];       // W_ih bf16 (84 KB)
    __shared__ unsigned short At[2 * TROWS * LST]; // emb dbuf (2 x 21 KB)

    const int t   = threadIdx.x;
    const int bid = blockIdx.x;

    for (int c = t; c < 128 * 40; c += 512) {
        const int row = c / 40;
        const int ch  = c - row * 40;
        const float* src = Wih + (size_t)row * DIM;
        const int k0 = ch * 8;
        unsigned p0, p1, p2, p3;
        if (k0 + 8 <= DIM) {
            const float4 a = *(const float4*)(src + k0);
            const float4 b = *(const float4*)(src + k0 + 4);
            p0 = bf16_rtne(a.x) | (bf16_rtne(a.y) << 16);
            p1 = bf16_rtne(a.z) | (bf16_rtne(a.w) << 16);
            p2 = bf16_rtne(b.x) | (bf16_rtne(b.y) << 16);
            p3 = bf16_rtne(b.z) | (bf16_rtne(b.w) << 16);
        } else {
            unsigned q[8];
            #pragma unroll
            for (int e = 0; e < 8; ++e) {
                const int k = k0 + e;
                q[e] = (k < DIM) ? bf16_rtne(src[k]) : 0u;
            }
            p0 = q[0] | (q[1] << 16);  p1 = q[2] | (q[3] << 16);
            p2 = q[4] | (q[5] << 16);  p3 = q[6] | (q[7] << 16);
        }
        uint4 o = {p0, p1, p2, p3};
        *(uint4*)(&Bt[row * LST + k0]) = o;
    }

#define STAGE_EMB(tl, bf) do {                                                \
        const int v0_ = (tl) * TROWS;                                         \
        for (int c = t; c < TROWS * 40; c += 512) {                           \
            const int row = c / 40;                                           \
            const int ch  = c - row * 40;                                     \
            int grow = v0_ + row; if (grow > VOCAB - 1) grow = VOCAB - 1;     \
            const float* src = emb + (size_t)grow * DIM;                      \
            const int k0 = ch * 8;                                            \
            unsigned p0, p1, p2, p3;                                          \
            if (k0 + 8 <= DIM) {                                              \
                const float4 a = *(const float4*)(src + k0);                  \
                const float4 b = *(const float4*)(src + k0 + 4);              \
                p0 = bf16_rtne(a.x) | (bf16_rtne(a.y) << 16);                 \
                p1 = bf16_rtne(a.z) | (bf16_rtne(a.w) << 16);                 \
                p2 = bf16_rtne(b.x) | (bf16_rtne(b.y) << 16);                 \
                p3 = bf16_rtne(b.z) | (bf16_rtne(b.w) << 16);                 \
            } else {                                                          \
                unsigned q[8];                                                \
                _Pragma("unroll")                                             \
                for (int e = 0; e < 8; ++e) {                                 \
                    const int k = k0 + e;                                     \
                    q[e] = (k < DIM) ? bf16_rtne(src[k]) : 0u;                \
                }                                                             \
                p0 = q[0] | (q[1] << 16);  p1 = q[2] | (q[3] << 16);          \
                p2 = q[4] | (q[5] << 16);  p3 = q[6] | (q[7] << 16);          \
            }                                                                 \
            uint4 o = {p0, p1, p2, p3};                                       \
            *(uint4*)(&At[(bf) * (TROWS * LST) + row * LST + k0]) = o;        \
        }                                                                     \
    } while (0)

    const int lane = t & 63;
    const int w    = t >> 6;
    const int mt   = w >> 2;
    const int np   = w & 3;
    const int lm   = lane & 15;
    const int kg   = lane >> 4;

    STAGE_EMB(bid, 0);
    __syncthreads();

    int buf = 0;
    for (int tile = bid; tile < NTILES; tile += 256) {
        if (tile + 256 < NTILES) STAGE_EMB(tile + 256, buf ^ 1);

        const unsigned short* arow = &At[buf * (TROWS * LST)
                                         + (mt * 16 + lm) * LST + kg * 8];
        const unsigned short* brow = &Bt[(np * 32 + lm) * LST + kg * 8];

        f32x4 acc0 = {0.f,0.f,0.f,0.f}, acc1 = {0.f,0.f,0.f,0.f};
        #pragma unroll
        for (int k0 = 0; k0 < KP; k0 += 32) {
            const bf16x8 af = *(const bf16x8*)(arow + k0);
            const bf16x8 b0 = *(const bf16x8*)(brow + k0);
            const bf16x8 b1 = *(const bf16x8*)(brow + 16 * LST + k0);
            acc0 = __builtin_amdgcn_mfma_f32_16x16x32_bf16(af, b0, acc0, 0, 0, 0);
            acc1 = __builtin_amdgcn_mfma_f32_16x16x32_bf16(af, b1, acc1, 0, 0, 0);
        }

        const int rbase = tile * TROWS + mt * 16 + kg * 4;
        #pragma unroll
        for (int nt2 = 0; nt2 < 2; ++nt2) {
            const int h = (np * 2 + nt2) * 16 + lm;
            const float bb = bih[h] + bhh[h];
            const f32x4 a = nt2 ? acc1 : acc0;
            #pragma unroll
            for (int r = 0; r < 4; ++r) {
                const int row = rbase + r;
                if (row < VOCAB) P[(size_t)row * HID + h] = a[r] + bb;
            }
        }

        __syncthreads();
        buf ^= 1;
    }
#undef STAGE_EMB
}

// ---------------------------------------------------------------------------
// Kernel B: RNN, oct-cooperative: oct o=t>>3 owns rows 2o,2o+1; lane ke=t&7
// covers k in [16ke,16ke+16) read ONCE (2 x b128 f16) and fed to BOTH rows
// (16 fdot2). LDS h-bytes/step: 32KB -> 16KB. 8-lane reduce: quad_sum DPP
// + row_half_mirror (0x141) DPP — post-quad-sum the half-row mirror is the
// partner quad WITHIN the oct. h write: predicated ds_write_b16 from lanes
// ke in {0,4} (16 addrs/wave, 2B apart -> 2-way, free). Chassis = R8/R18.
// ---------------------------------------------------------------------------
__device__ __forceinline__ float quad_sum(float v)
{
    int x1 = __builtin_amdgcn_update_dpp(0, __float_as_int(v), 0xB1, 0xF, 0xF, true);
    v += __int_as_float(x1);
    int x2 = __builtin_amdgcn_update_dpp(0, __float_as_int(v), 0x4E, 0xF, 0xF, true);
    v += __int_as_float(x2);
    return v;
}
__device__ __forceinline__ float oct_sum(float v)
{
    v = quad_sum(v);
    int m = __builtin_amdgcn_update_dpp(0, __float_as_int(v), 0x141, 0xF, 0xF, true);
    return v + __int_as_float(m);   // row_half_mirror: partner quad in oct
}

__device__ __forceinline__ half2_t u2h(unsigned u)
{
    union { unsigned u; half2_t h; } c; c.u = u; return c.h;
}

__global__ __launch_bounds__(512)
void rnn_kernel(const int* __restrict__ x,
                const float* __restrict__ Whh,
                const float* __restrict__ P,
                const float* __restrict__ fcw,
                const float* __restrict__ fcb,
                float* __restrict__ out)
{
    __shared__ __align__(16) unsigned short h0b[HID];   // f16 h (256 B)
    __shared__ __align__(16) unsigned short h1b[HID];
    __shared__ int   toff[SEQ];
    __shared__ float xb[2 * 64 * HID];
    __shared__ float red[HID];

    const int t  = threadIdx.x;
    const int b  = blockIdx.x;
    const int o  = t >> 3;          // oct 0..63 -> rows 2o, 2o+1
    const int ke = t & 7;           // k-range [16ke, 16ke+16)
    const int r0 = 2 * o;
    const int r1 = 2 * o + 1;

    toff[t] = x[b * SEQ + t] * HID;
    if (t < HID) h0b[t] = 0;   // f16 zero

    // W rows r0, r1, k-range [16ke,16ke+16) as 8 f16 pairs each
    half2_t wh0[8], wh1[8];
    {
        const float* wr0 = Whh + (size_t)r0 * HID + ke * 16;
        const float* wr1 = Whh + (size_t)r1 * HID + ke * 16;
        #pragma unroll
        for (int j = 0; j < 4; ++j) {
            const float4 a = *(const float4*)(wr0 + j * 4);
            wh0[2*j]   = __builtin_amdgcn_cvt_pkrtz(a.x, a.y);
            wh0[2*j+1] = __builtin_amdgcn_cvt_pkrtz(a.z, a.w);
            const float4 c = *(const float4*)(wr1 + j * 4);
            wh1[2*j]   = __builtin_amdgcn_cvt_pkrtz(c.x, c.y);
            wh1[2*j+1] = __builtin_amdgcn_cvt_pkrtz(c.z, c.w);
        }
    }
    __syncthreads();

#define STAGE(cn) do {                                                        \
        const int w_ = t >> 6, l_ = t & 63;                                   \
        const int base_ = ((cn) & 1) * (64 * HID);                            \
        _Pragma("unroll")                                                     \
        for (int q_ = 0; q_ < 4; ++q_) {                                      \
            const int row_ = w_ * 8 + q_ * 2 + (l_ >> 5);                     \
            const int col_ = (l_ & 31) * 4;                                   \
            const int off_ = toff[(cn) * 64 + row_] + col_;                   \
            const float4 v_ = *(const float4*)(P + off_);                     \
            *(float4*)(&xb[base_ + row_ * HID + col_]) = v_;                  \
        }                                                                     \
    } while (0)

    STAGE(0);
    __syncthreads();

    float hmax0 = -3.0e38f, hsum0 = 0.f;
    float hmax1 = -3.0e38f, hsum1 = 0.f;

#define STEP(HRD, HWR, XPTR, SOFF) do {                                       \
        const float xt0 = (XPTR)[(SOFF) * HID];                               \
        const float xt1 = (XPTR)[(SOFF) * HID + 1];                           \
        const uint4 qa = *(const uint4*)((HRD) + ke * 16);                    \
        const uint4 qb = *(const uint4*)((HRD) + ke * 16 + 8);                \
        float a00 = 0.f, a01 = 0.f, a10 = 0.f, a11 = 0.f;                     \
        a00 = __builtin_amdgcn_fdot2(wh0[0], u2h(qa.x), a00, false);          \
        a10 = __builtin_amdgcn_fdot2(wh1[0], u2h(qa.x), a10, false);          \
        a00 = __builtin_amdgcn_fdot2(wh0[1], u2h(qa.y), a00, false);          \
        a10 = __builtin_amdgcn_fdot2(wh1[1], u2h(qa.y), a10, false);          \
        a00 = __builtin_amdgcn_fdot2(wh0[2], u2h(qa.z), a00, false);          \
        a10 = __builtin_amdgcn_fdot2(wh1[2], u2h(qa.z), a10, false);          \
        a00 = __builtin_amdgcn_fdot2(wh0[3], u2h(qa.w), a00, false);          \
        a10 = __builtin_amdgcn_fdot2(wh1[3], u2h(qa.w), a10, false);          \
        a01 = __builtin_amdgcn_fdot2(wh0[4], u2h(qb.x), a01, false);          \
        a11 = __builtin_amdgcn_fdot2(wh1[4], u2h(qb.x), a11, false);          \
        a01 = __builtin_amdgcn_fdot2(wh0[5], u2h(qb.y), a01, false);          \
        a11 = __builtin_amdgcn_fdot2(wh1[5], u2h(qb.y), a11, false);          \
        a01 = __builtin_amdgcn_fdot2(wh0[6], u2h(qb.z), a01, false);          \
        a11 = __builtin_amdgcn_fdot2(wh1[6], u2h(qb.z), a11, false);          \
        a01 = __builtin_amdgcn_fdot2(wh0[7], u2h(qb.w), a01, false);          \
        a11 = __builtin_amdgcn_fdot2(wh1[7], u2h(qb.w), a11, false);          \
        const float s0 = oct_sum(a00 + a01);                                  \
        const float s1 = oct_sum(a10 + a11);                                  \
        const float z0 = xt0 + s0;                                            \
        const float z1 = xt1 + s1;                                            \
        const float e0 = __builtin_amdgcn_exp2f(z0 * 2.8853900817779268f);    \
        const float h0n = fmaf(-2.f, __builtin_amdgcn_rcpf(e0 + 1.f), 1.f);   \
        const float e1 = __builtin_amdgcn_exp2f(z1 * 2.8853900817779268f);    \
        const float h1n = fmaf(-2.f, __builtin_amdgcn_rcpf(e1 + 1.f), 1.f);   \
        hmax0 = fmaxf(hmax0, h0n); hsum0 += h0n;                              \
        hmax1 = fmaxf(hmax1, h1n); hsum1 += h1n;                              \
        if ((ke & 3) == 0) {                                                  \
            const int hi_ = ke >> 2;                                          \
            union { __fp16 f; unsigned short u; } cv_;                        \
            cv_.f = (__fp16)(hi_ ? h1n : h0n);                                \
            (HWR)[hi_ ? r1 : r0] = cv_.u;                                     \
        }                                                                     \
        __syncthreads();                                                      \
    } while (0)

    for (int c = 0; c < 8; ++c) {
        if (c < 7) STAGE(c + 1);
        const float* xp = &xb[(c & 1) * (64 * HID) + r0];
        #pragma unroll 4
        for (int u = 0; u < 32; ++u) {
            STEP(h0b, h1b, xp, u * 2);
            STEP(h1b, h0b, xp, u * 2 + 1);
        }
    }
#undef STEP
#undef STAGE

    // pooling + FC: lanes ke==0 -> row r0, ke==4 -> row r1
    if ((ke & 3) == 0) {
        const int hi = ke >> 2;
        const int r  = hi ? r1 : r0;
        const float hm = hi ? hmax1 : hmax0;
        const float hs = hi ? hsum1 : hsum0;
        red[r] = fcw[r] * hm + fcw[HID + r] * (hs * (1.f / 512.f));
    }
    __syncthreads();
    if (t < 64) {
        float v = red[t] + red[t + 64];
        #pragma unroll
        for (int m = 32; m >= 1; m >>= 1) v += __shfl_xor(v, m);
        if (t == 0) out[b] = v + fcb[0];
    }
}

// ---------------------------------------------------------------------------
extern "C" void kernel_launch(void* const* d_in, const int* in_sizes, int n_in,
                              void* d_out, int out_size, void* d_ws, size_t ws_size,
                              hipStream_t stream)
{
    const int*   x   = (const int*)  d_in[0];
    const float* emb = (const float*)d_in[1];
    const float* Wih = (const float*)d_in[2];
    const float* Whh = (const float*)d_in[3];
    const float* bih = (const float*)d_in[4];
    const float* bhh = (const float*)d_in[5];
    const float* fcw = (const float*)d_in[6];
    const float* fcb = (const float*)d_in[7];

    float* P = (float*)d_ws;   // exactly VOCAB*HID*4 = 25.6 MB (R1-proven)

    proj_persist<<<256, 512, 0, stream>>>(emb, Wih, bih, bhh, P);
    rnn_kernel<<<BATCH, 512, 0, stream>>>(x, Whh, P, fcw, fcb, (float*)d_out);
}

// Round 20
// 182.490 us; speedup vs baseline: 1.1004x; 1.1004x over previous
//
#include <hip/hip_runtime.h>

#define HID    128
#define SEQ    512
#define BATCH  256
#define DIM    300
#define VOCAB  50000

typedef short bf16x8 __attribute__((ext_vector_type(8)));   // 8 bf16 = 4 VGPR
typedef float f32x4  __attribute__((ext_vector_type(4)));
typedef __fp16 half2_t __attribute__((ext_vector_type(2))); // matches cvt_pkrtz

#define KP     320      // padded K (10 x 32)
#define LST    328      // LDS row stride in bf16 (656 B, 16B-aligned)
#define TROWS  32       // vocab rows per tile
#define NTILES ((VOCAB + TROWS - 1) / TROWS)   // 1563

__device__ __forceinline__ unsigned bf16_rtne(float v)
{
    unsigned u = __float_as_uint(v);
    return (u + 0x7FFFu + ((u >> 16) & 1u)) >> 16;
}

// ---------------------------------------------------------------------------
// Kernel A (R15-proven, ~33 µs): persistent MFMA proj — byte-identical.
// ---------------------------------------------------------------------------
__global__ __launch_bounds__(512)
void proj_persist(const float* __restrict__ emb,
                  const float* __restrict__ Wih,
                  const float* __restrict__ bih,
                  const float* __restrict__ bhh,
                  float* __restrict__ P)
{
    __shared__ unsigned short Bt[128 * LST];       // W_ih bf16 (84 KB)
    __shared__ unsigned short At[2 * TROWS * LST]; // emb dbuf (2 x 21 KB)

    const int t   = threadIdx.x;
    const int bid = blockIdx.x;

    for (int c = t; c < 128 * 40; c += 512) {
        const int row = c / 40;
        const int ch  = c - row * 40;
        const float* src = Wih + (size_t)row * DIM;
        const int k0 = ch * 8;
        unsigned p0, p1, p2, p3;
        if (k0 + 8 <= DIM) {
            const float4 a = *(const float4*)(src + k0);
            const float4 b = *(const float4*)(src + k0 + 4);
            p0 = bf16_rtne(a.x) | (bf16_rtne(a.y) << 16);
            p1 = bf16_rtne(a.z) | (bf16_rtne(a.w) << 16);
            p2 = bf16_rtne(b.x) | (bf16_rtne(b.y) << 16);
            p3 = bf16_rtne(b.z) | (bf16_rtne(b.w) << 16);
        } else {
            unsigned q[8];
            #pragma unroll
            for (int e = 0; e < 8; ++e) {
                const int k = k0 + e;
                q[e] = (k < DIM) ? bf16_rtne(src[k]) : 0u;
            }
            p0 = q[0] | (q[1] << 16);  p1 = q[2] | (q[3] << 16);
            p2 = q[4] | (q[5] << 16);  p3 = q[6] | (q[7] << 16);
        }
        uint4 o = {p0, p1, p2, p3};
        *(uint4*)(&Bt[row * LST + k0]) = o;
    }

#define STAGE_EMB(tl, bf) do {                                                \
        const int v0_ = (tl) * TROWS;                                         \
        for (int c = t; c < TROWS * 40; c += 512) {                           \
            const int row = c / 40;                                           \
            const int ch  = c - row * 40;                                     \
            int grow = v0_ + row; if (grow > VOCAB - 1) grow = VOCAB - 1;     \
            const float* src = emb + (size_t)grow * DIM;                      \
            const int k0 = ch * 8;                                            \
            unsigned p0, p1, p2, p3;                                          \
            if (k0 + 8 <= DIM) {                                              \
                const float4 a = *(const float4*)(src + k0);                  \
                const float4 b = *(const float4*)(src + k0 + 4);              \
                p0 = bf16_rtne(a.x) | (bf16_rtne(a.y) << 16);                 \
                p1 = bf16_rtne(a.z) | (bf16_rtne(a.w) << 16);                 \
                p2 = bf16_rtne(b.x) | (bf16_rtne(b.y) << 16);                 \
                p3 = bf16_rtne(b.z) | (bf16_rtne(b.w) << 16);                 \
            } else {                                                          \
                unsigned q[8];                                                \
                _Pragma("unroll")                                             \
                for (int e = 0; e < 8; ++e) {                                 \
                    const int k = k0 + e;                                     \
                    q[e] = (k < DIM) ? bf16_rtne(src[k]) : 0u;                \
                }                                                             \
                p0 = q[0] | (q[1] << 16);  p1 = q[2] | (q[3] << 16);          \
                p2 = q[4] | (q[5] << 16);  p3 = q[6] | (q[7] << 16);          \
            }                                                                 \
            uint4 o = {p0, p1, p2, p3};                                       \
            *(uint4*)(&At[(bf) * (TROWS * LST) + row * LST + k0]) = o;        \
        }                                                                     \
    } while (0)

    const int lane = t & 63;
    const int w    = t >> 6;
    const int mt   = w >> 2;
    const int np   = w & 3;
    const int lm   = lane & 15;
    const int kg   = lane >> 4;

    STAGE_EMB(bid, 0);
    __syncthreads();

    int buf = 0;
    for (int tile = bid; tile < NTILES; tile += 256) {
        if (tile + 256 < NTILES) STAGE_EMB(tile + 256, buf ^ 1);

        const unsigned short* arow = &At[buf * (TROWS * LST)
                                         + (mt * 16 + lm) * LST + kg * 8];
        const unsigned short* brow = &Bt[(np * 32 + lm) * LST + kg * 8];

        f32x4 acc0 = {0.f,0.f,0.f,0.f}, acc1 = {0.f,0.f,0.f,0.f};
        #pragma unroll
        for (int k0 = 0; k0 < KP; k0 += 32) {
            const bf16x8 af = *(const bf16x8*)(arow + k0);
            const bf16x8 b0 = *(const bf16x8*)(brow + k0);
            const bf16x8 b1 = *(const bf16x8*)(brow + 16 * LST + k0);
            acc0 = __builtin_amdgcn_mfma_f32_16x16x32_bf16(af, b0, acc0, 0, 0, 0);
            acc1 = __builtin_amdgcn_mfma_f32_16x16x32_bf16(af, b1, acc1, 0, 0, 0);
        }

        const int rbase = tile * TROWS + mt * 16 + kg * 4;
        #pragma unroll
        for (int nt2 = 0; nt2 < 2; ++nt2) {
            const int h = (np * 2 + nt2) * 16 + lm;
            const float bb = bih[h] + bhh[h];
            const f32x4 a = nt2 ? acc1 : acc0;
            #pragma unroll
            for (int r = 0; r < 4; ++r) {
                const int row = rbase + r;
                if (row < VOCAB) P[(size_t)row * HID + h] = a[r] + bb;
            }
        }

        __syncthreads();
        buf ^= 1;
    }
#undef STAGE_EMB
}

// ---------------------------------------------------------------------------
// Kernel B (R18-proven, 145 µs): RNN, R8 chassis, h as F16 pairs in LDS +
// v_dot2_f32_f16 (no unpack chain). W pre-converted via cvt_pkrtz.
// ---------------------------------------------------------------------------
__device__ __forceinline__ float quad_sum(float v)
{
    int x1 = __builtin_amdgcn_update_dpp(0, __float_as_int(v), 0xB1, 0xF, 0xF, true);
    v += __int_as_float(x1);
    int x2 = __builtin_amdgcn_update_dpp(0, __float_as_int(v), 0x4E, 0xF, 0xF, true);
    v += __int_as_float(x2);
    return v;
}

#if defined(__has_builtin)
#  if __has_builtin(__builtin_amdgcn_fdot2)
#    define HAVE_FDOT2 1
#  endif
#endif

__device__ __forceinline__ half2_t u2h(unsigned u)
{
    union { unsigned u; half2_t h; } c; c.u = u; return c.h;
}

__global__ __launch_bounds__(512)
void rnn_kernel(const int* __restrict__ x,
                const float* __restrict__ Whh,
                const float* __restrict__ P,
                const float* __restrict__ fcw,
                const float* __restrict__ fcb,
                float* __restrict__ out)
{
    __shared__ __align__(16) unsigned short h0b[HID];   // f16 h (256 B)
    __shared__ __align__(16) unsigned short h1b[HID];
    __shared__ int   toff[SEQ];
    __shared__ float xb[2 * 64 * HID];
    __shared__ float red[HID];

    const int t  = threadIdx.x;
    const int b  = blockIdx.x;
    const int i  = t >> 2;
    const int kq = t & 3;

    toff[t] = x[b * SEQ + t] * HID;
    if (t < HID) h0b[t] = 0;   // f16 zero

    // W_hh[i][kq*32 + pj*8 .. +8] as 16 packed f16 pairs (pj=(j+kq)&3)
    half2_t wh[16];
    #pragma unroll
    for (int j = 0; j < 4; ++j) {
        const int pj = (j + kq) & 3;
        const float4 vA = *(const float4*)(Whh + (size_t)i * HID + kq * 32 + pj * 8);
        const float4 vB = *(const float4*)(Whh + (size_t)i * HID + kq * 32 + pj * 8 + 4);
        wh[j*4+0] = __builtin_amdgcn_cvt_pkrtz(vA.x, vA.y);
        wh[j*4+1] = __builtin_amdgcn_cvt_pkrtz(vA.z, vA.w);
        wh[j*4+2] = __builtin_amdgcn_cvt_pkrtz(vB.x, vB.y);
        wh[j*4+3] = __builtin_amdgcn_cvt_pkrtz(vB.z, vB.w);
    }
    __syncthreads();

#define STAGE(cn) do {                                                        \
        const int w_ = t >> 6, l_ = t & 63;                                   \
        const int base_ = ((cn) & 1) * (64 * HID);                            \
        _Pragma("unroll")                                                     \
        for (int q_ = 0; q_ < 4; ++q_) {                                      \
            const int row_ = w_ * 8 + q_ * 2 + (l_ >> 5);                     \
            const int col_ = (l_ & 31) * 4;                                   \
            const int off_ = toff[(cn) * 64 + row_] + col_;                   \
            const float4 v_ = *(const float4*)(P + off_);                     \
            *(float4*)(&xb[base_ + row_ * HID + col_]) = v_;                  \
        }                                                                     \
    } while (0)

    STAGE(0);
    __syncthreads();

    float hmax = -3.0e38f, hsum = 0.f;

#if HAVE_FDOT2
#define JBLK(HRD, J, AC) do {                                                 \
        const int pj_ = ((J) + kq) & 3;                                       \
        const uint4 q_ = *(const uint4*)((HRD) + kq * 32 + pj_ * 8);          \
        AC = __builtin_amdgcn_fdot2(wh[(J)*4+0], u2h(q_.x), AC, false);       \
        AC = __builtin_amdgcn_fdot2(wh[(J)*4+1], u2h(q_.y), AC, false);       \
        AC = __builtin_amdgcn_fdot2(wh[(J)*4+2], u2h(q_.z), AC, false);       \
        AC = __builtin_amdgcn_fdot2(wh[(J)*4+3], u2h(q_.w), AC, false);       \
    } while (0)
#else
#define JBLK(HRD, J, AC) do {                                                 \
        const int pj_ = ((J) + kq) & 3;                                       \
        const uint4 q_ = *(const uint4*)((HRD) + kq * 32 + pj_ * 8);          \
        _Pragma("unroll")                                                     \
        for (int e_ = 0; e_ < 4; ++e_) {                                      \
            const unsigned u_ = (e_==0)?q_.x:(e_==1)?q_.y:(e_==2)?q_.z:q_.w;  \
            const half2_t h2_ = u2h(u_);                                      \
            AC = fmaf((float)wh[(J)*4+e_].x, (float)h2_.x, AC);               \
            AC = fmaf((float)wh[(J)*4+e_].y, (float)h2_.y, AC);               \
        }                                                                     \
    } while (0)
#endif

#define STEP(HRD, HWR, XPTR, SOFF) do {                                       \
        const float xt = (XPTR)[(SOFF) * HID];                                \
        float ac0 = 0.f, ac1 = 0.f, ac2 = 0.f, ac3 = 0.f;                     \
        JBLK(HRD, 0, ac0);                                                    \
        JBLK(HRD, 1, ac1);                                                    \
        JBLK(HRD, 2, ac2);                                                    \
        JBLK(HRD, 3, ac3);                                                    \
        float acc = (ac0 + ac1) + (ac2 + ac3);                                \
        acc = quad_sum(acc);                                                  \
        const float z = xt + acc;                                             \
        const float e = __builtin_amdgcn_exp2f(z * 2.8853900817779268f);      \
        const float hnew = fmaf(-2.f, __builtin_amdgcn_rcpf(e + 1.f), 1.f);   \
        hmax = fmaxf(hmax, hnew);                                             \
        hsum += hnew;                                                         \
        union { __fp16 f; unsigned short u; } cv_;                            \
        cv_.f = (__fp16)hnew;                                                 \
        (HWR)[i] = cv_.u;   /* 4 dup lanes: same value, same address */       \
        __syncthreads();                                                      \
    } while (0)

    for (int c = 0; c < 8; ++c) {
        if (c < 7) STAGE(c + 1);
        const float* xp = &xb[(c & 1) * (64 * HID) + i];
        #pragma unroll 4
        for (int u = 0; u < 32; ++u) {
            STEP(h0b, h1b, xp, u * 2);
            STEP(h1b, h0b, xp, u * 2 + 1);
        }
    }
#undef STEP
#undef JBLK
#undef STAGE

    if (kq == 0)
        red[i] = fcw[i] * hmax + fcw[HID + i] * (hsum * (1.f / 512.f));
    __syncthreads();
    if (t < 64) {
        float v = red[t] + red[t + 64];
        #pragma unroll
        for (int m = 32; m >= 1; m >>= 1) v += __shfl_xor(v, m);
        if (t == 0) out[b] = v + fcb[0];
    }
}

// ---------------------------------------------------------------------------
extern "C" void kernel_launch(void* const* d_in, const int* in_sizes, int n_in,
                              void* d_out, int out_size, void* d_ws, size_t ws_size,
                              hipStream_t stream)
{
    const int*   x   = (const int*)  d_in[0];
    const float* emb = (const float*)d_in[1];
    const float* Wih = (const float*)d_in[2];
    const float* Whh = (const float*)d_in[3];
    const float* bih = (const float*)d_in[4];
    const float* bhh = (const float*)d_in[5];
    const float* fcw = (const float*)d_in[6];
    const float* fcb = (const float*)d_in[7];

    float* P = (float*)d_ws;   // exactly VOCAB*HID*4 = 25.6 MB (R1-proven)

    proj_persist<<<256, 512, 0, stream>>>(emb, Wih, bih, bhh, P);
    rnn_kernel<<<BATCH, 512, 0, stream>>>(x, Whh, P, fcw, fcb, (float*)d_out);
}